// Round 7
// baseline (224.409 us; speedup 1.0000x reference)
//
#include <hip/hip_runtime.h>

#define HID 256
#define NH 4
#define NEG 0.2f

typedef __attribute__((ext_vector_type(8))) short short8;
typedef __attribute__((ext_vector_type(4))) float f32x4;

__device__ __forceinline__ unsigned short f2b(float f) {
    unsigned u = __float_as_uint(f);
    u = u + 0x7FFFu + ((u >> 16) & 1u);
    return (unsigned short)(u >> 16);
}
__device__ __forceinline__ float b2f_lo(unsigned u) {
    return __uint_as_float(u << 16);
}
__device__ __forceinline__ float b2f_hi(unsigned u) {
    return __uint_as_float(u & 0xFFFF0000u);
}
__device__ __forceinline__ float lrelu(float f) {
    return f > 0.f ? f : NEG * f;
}

// ---- K_zero: zero deg8 (N*8 ints) ----
__global__ __launch_bounds__(256) void k_zero(int4* __restrict__ deg8v,
                                              int n4) {
    int i = blockIdx.x * 256 + threadIdx.x;
    if (i < n4) deg8v[i] = make_int4(0, 0, 0, 0);
}

// ---- K_prep: [edge slot-capture (8-way split) | x->Ap pack | W->Bp pack |
//               wedot] ----
// frag layout: Ap[((fi*8+ks)*64+lane)*8+j] = A[fi*16+(lane&15)][ks*32+(lane>>4)*8+j]
__global__ __launch_bounds__(256) void k_prep(
    const float* __restrict__ x, const float* __restrict__ W,
    const float* __restrict__ We, const float* __restrict__ att_edge,
    const int* __restrict__ dst,
    unsigned short* __restrict__ Ap, unsigned short* __restrict__ Bp,
    float* __restrict__ wedot, int* __restrict__ deg8, int* __restrict__ pos,
    int N, int E, int DBc, int XB) {
    __shared__ unsigned short sm[4096];
    int b = blockIdx.x, t = threadIdx.x;
    if (b < DBc) {  // ---- slot capture: 2 edges/thread, 8-way split ----
        int e0 = b * 512 + t;
        int e1 = e0 + 256;
        if (e1 < E) {
            int d0 = dst[e0], d1 = dst[e1];
            int p0 = atomicAdd(&deg8[(d0 << 3) | (e0 & 7)], 1);
            int p1 = atomicAdd(&deg8[(d1 << 3) | (e1 & 7)], 1);
            pos[e0] = p0;
            pos[e1] = p1;
        } else if (e0 < E) {
            int d0 = dst[e0];
            pos[e0] = atomicAdd(&deg8[(d0 << 3) | (e0 & 7)], 1);
        }
        return;
    }
    int b2 = b - DBc;
    if (b2 < XB) {  // ---- pack x: one 16-row tile -> 8KB contiguous ----
        int fi = b2;
        int r = t >> 4;
        int row = fi * 16 + r;
        const float4* x4 = (const float4*)x;
        #pragma unroll
        for (int q = 0; q < 4; q++) {
            int c4 = (t & 15) + (q << 4);
            unsigned u0 = 0, u1 = 0;
            if (row < N) {
                float4 v = x4[(size_t)row * 64 + c4];
                u0 = (unsigned)f2b(v.x) | ((unsigned)f2b(v.y) << 16);
                u1 = (unsigned)f2b(v.z) | ((unsigned)f2b(v.w) << 16);
            }
            int k0 = c4 << 2;
            int ks = k0 >> 5, ko = k0 & 31;
            int lane = r + ((ko >> 3) << 4);
            int off = ks * 512 + lane * 8 + (ko & 7);
            *((uint2*)&sm[off]) = make_uint2(u0, u1);
        }
        __syncthreads();
        uint4* out = (uint4*)(Ap + (size_t)fi * 4096);
        const uint4* smv = (const uint4*)sm;
        out[t] = smv[t];
        out[256 + t] = smv[256 + t];
    } else if (b2 < XB + 16) {  // ---- pack W: one 16-col strip ----
        int n16 = b2 - XB;
        int k = t;
        int ks = k >> 5;
        int lhi = ((k & 31) >> 3) << 4;
        int j = k & 7;
        const float4* W4 = (const float4*)W;
        #pragma unroll
        for (int q = 0; q < 4; q++) {
            float4 v = W4[(size_t)k * 64 + n16 * 4 + q];
            int c = q << 2;
            sm[ks * 512 + (lhi + c + 0) * 8 + j] = f2b(v.x);
            sm[ks * 512 + (lhi + c + 1) * 8 + j] = f2b(v.y);
            sm[ks * 512 + (lhi + c + 2) * 8 + j] = f2b(v.z);
            sm[ks * 512 + (lhi + c + 3) * 8 + j] = f2b(v.w);
        }
        __syncthreads();
        uint4* out = (uint4*)(Bp + (size_t)n16 * 4096);
        const uint4* smv = (const uint4*)sm;
        out[t] = smv[t];
        out[256 + t] = smv[256 + t];
    } else {  // ---- wedot ----
        float v = We[t] * att_edge[t];
        #pragma unroll
        for (int off = 32; off; off >>= 1) v += __shfl_down(v, off);
        if ((t & 63) == 0) wedot[t >> 6] = v;
    }
}

// ---- K_scan8: exclusive prefix scan of deg8[N*8] -> rowptr8 ----
__global__ __launch_bounds__(1024) void k_scan8(const int* __restrict__ deg8,
                                                int* __restrict__ rowptr8,
                                                int M) {
    __shared__ int wsum[16], woff[16];
    int t = threadIdx.x, lane = t & 63, w = t >> 6;
    int ch = (M + 1023) >> 10;
    int base = t * ch;
    int s = 0;
    for (int u = 0; u < ch; u++) {
        int i = base + u;
        if (i < M) s += deg8[i];
    }
    int incl = s;
    #pragma unroll
    for (int off = 1; off < 64; off <<= 1) {
        int up = __shfl_up(incl, off);
        if (lane >= off) incl += up;
    }
    if (lane == 63) wsum[w] = incl;
    __syncthreads();
    if (t < 16) {
        int v = wsum[t];
        int inc = v;
        #pragma unroll
        for (int off = 1; off < 16; off <<= 1) {
            int up = __shfl_up(inc, off);
            if (t >= off) inc += up;
        }
        woff[t] = inc - v;
    }
    __syncthreads();
    int run = woff[w] + (incl - s);
    for (int u = 0; u < ch; u++) {
        int i = base + u;
        if (i < M) {
            int v = deg8[i];
            rowptr8[i] = run;
            run += v;
        }
    }
    if (base <= M - 1 && M - 1 < base + ch) rowptr8[M] = run;
}

// ---- K_fillmm: fused [mfma xp=x@W + a_s/a_d epilogue | CSR scatter] ----
__global__ __launch_bounds__(256) void k_fillmm(
    const unsigned short* __restrict__ Ap, const unsigned short* __restrict__ Bp,
    const float* __restrict__ att_src, const float* __restrict__ att_dst,
    unsigned short* __restrict__ xp, float* __restrict__ a_s,
    float* __restrict__ a_d, const int* __restrict__ src,
    const int* __restrict__ dst, const float* __restrict__ eattr,
    const int* __restrict__ rowptr8, const int* __restrict__ pos,
    int2* __restrict__ adj, int N, int MF, int MB, int E) {
    int t = threadIdx.x;
    if ((int)blockIdx.x >= MB) {  // ---- CSR scatter (atomic-free) ----
        int fb = blockIdx.x - MB;
        int e0 = fb * 512 + t;
        int e1 = e0 + 256;
        if (e0 < E) {
            int d = dst[e0];
            int slot = rowptr8[(d << 3) | (e0 & 7)] + pos[e0];
            adj[slot] = make_int2(src[e0], __float_as_int(eattr[e0]));
        }
        if (e1 < E) {
            int d = dst[e1];
            int slot = rowptr8[(d << 3) | (e1 & 7)] + pos[e1];
            adj[slot] = make_int2(src[e1], __float_as_int(eattr[e1]));
        }
        return;
    }
    int w = t >> 6, l = t & 63;
    int fi0 = blockIdx.x * 4;
    const short8* A8 = (const short8*)Ap;
    const short8* B8 = (const short8*)Bp;
    f32x4 acc[4][4];
    #pragma unroll
    for (int mi = 0; mi < 4; mi++)
        #pragma unroll
        for (int ni = 0; ni < 4; ni++)
            acc[mi][ni] = (f32x4){0.f, 0.f, 0.f, 0.f};
    short8 zz = {0, 0, 0, 0, 0, 0, 0, 0};
    #pragma unroll
    for (int ks = 0; ks < 8; ks++) {
        short8 a[4], b[4];
        #pragma unroll
        for (int mi = 0; mi < 4; mi++) {
            int fi = fi0 + mi;
            a[mi] = (fi < MF) ? A8[(size_t)(fi * 8 + ks) * 64 + l] : zz;
        }
        #pragma unroll
        for (int ni = 0; ni < 4; ni++)
            b[ni] = B8[(size_t)(((w << 2) + ni) * 8 + ks) * 64 + l];
        #pragma unroll
        for (int mi = 0; mi < 4; mi++)
            #pragma unroll
            for (int ni = 0; ni < 4; ni++)
                acc[mi][ni] = __builtin_amdgcn_mfma_f32_16x16x32_bf16(
                    a[mi], b[ni], acc[mi][ni], 0, 0, 0);
    }
    int colb = w << 6;
    float asc[4], adc[4];
    #pragma unroll
    for (int ni = 0; ni < 4; ni++) {
        asc[ni] = att_src[colb + ni * 16 + (l & 15)];
        adc[ni] = att_dst[colb + ni * 16 + (l & 15)];
    }
    #pragma unroll
    for (int mi = 0; mi < 4; mi++) {
        int rowb = fi0 * 16 + mi * 16 + ((l >> 4) << 2);
        #pragma unroll
        for (int r = 0; r < 4; r++) {
            int row = rowb + r;
            float ps = 0.f, pd = 0.f;
            #pragma unroll
            for (int ni = 0; ni < 4; ni++) {
                float v = acc[mi][ni][r];
                ps += v * asc[ni];
                pd += v * adc[ni];
            }
            #pragma unroll
            for (int off = 1; off < 16; off <<= 1) {
                ps += __shfl_xor(ps, off);
                pd += __shfl_xor(pd, off);
            }
            if (row < N) {
                if ((l & 15) == 0) {
                    a_s[(row << 2) + w] = ps;
                    a_d[(row << 2) + w] = pd;
                }
                #pragma unroll
                for (int ni = 0; ni < 4; ni++)
                    xp[(size_t)row * HID + colb + ni * 16 + (l & 15)] =
                        f2b(acc[mi][ni][r]);
            }
        }
    }
}

// ---- K_gather_ln: wave-per-node online-softmax gather; self-loop folded
//      in at the end (loop_ea computed from the edges themselves) ----
__global__ __launch_bounds__(256) void k_gather_ln(
    const int2* __restrict__ adj, const int* __restrict__ rowptr8,
    const float4* __restrict__ a_s4, const float4* __restrict__ a_d4,
    const float* __restrict__ wedot, const unsigned short* __restrict__ xp,
    const float4* __restrict__ x4, const float4* __restrict__ bias4,
    const float4* __restrict__ gamma4, const float4* __restrict__ beta4,
    float4* __restrict__ out4, int N) {
    __shared__ float4 sp[4][64];
    __shared__ int ssrc[4][64];
    int t = threadIdx.x;
    int u = t >> 6, l = t & 63, hl = l >> 4;
    int n = blockIdx.x * 4 + u;
    if (n >= N) return;
    int beg = rowptr8[n << 3];
    int cnt = rowptr8[(n + 1) << 3] - beg;
    float4 adn = a_d4[n];
    float4 wh = *(const float4*)wedot;
    float4 m4 = {-1e30f, -1e30f, -1e30f, -1e30f};
    float4 z4 = {0.f, 0.f, 0.f, 0.f};
    float acc0 = 0.f, acc1 = 0.f, acc2 = 0.f, acc3 = 0.f;
    float se = 0.f;
    int ntile = (cnt + 63) >> 6;
    for (int tile = 0; tile < ntile; tile++) {
        int j = (tile << 6) + l;
        float4 lg = {-1e30f, -1e30f, -1e30f, -1e30f};
        float ea = 0.f;
        int s = 0;
        if (j < cnt) {
            int2 a = adj[beg + j];
            s = a.x;
            ea = __int_as_float(a.y);
            float4 as_ = a_s4[s];
            lg.x = lrelu(as_.x + adn.x + ea * wh.x);
            lg.y = lrelu(as_.y + adn.y + ea * wh.y);
            lg.z = lrelu(as_.z + adn.z + ea * wh.z);
            lg.w = lrelu(as_.w + adn.w + ea * wh.w);
        }
        float4 cm = lg;
        float es = ea;
        #pragma unroll
        for (int off = 32; off; off >>= 1) {
            cm.x = fmaxf(cm.x, __shfl_xor(cm.x, off));
            cm.y = fmaxf(cm.y, __shfl_xor(cm.y, off));
            cm.z = fmaxf(cm.z, __shfl_xor(cm.z, off));
            cm.w = fmaxf(cm.w, __shfl_xor(cm.w, off));
            es += __shfl_xor(es, off);
        }
        se += es;
        float4 mn;
        mn.x = fmaxf(m4.x, cm.x);
        mn.y = fmaxf(m4.y, cm.y);
        mn.z = fmaxf(m4.z, cm.z);
        mn.w = fmaxf(m4.w, cm.w);
        float4 sc;
        sc.x = __expf(m4.x - mn.x);
        sc.y = __expf(m4.y - mn.y);
        sc.z = __expf(m4.z - mn.z);
        sc.w = __expf(m4.w - mn.w);
        float4 p;
        p.x = __expf(lg.x - mn.x);
        p.y = __expf(lg.y - mn.y);
        p.z = __expf(lg.z - mn.z);
        p.w = __expf(lg.w - mn.w);
        m4 = mn;
        float4 ps = p;
        #pragma unroll
        for (int off = 32; off; off >>= 1) {
            ps.x += __shfl_xor(ps.x, off);
            ps.y += __shfl_xor(ps.y, off);
            ps.z += __shfl_xor(ps.z, off);
            ps.w += __shfl_xor(ps.w, off);
        }
        z4.x = z4.x * sc.x + ps.x;
        z4.y = z4.y * sc.y + ps.y;
        z4.z = z4.z * sc.z + ps.z;
        z4.w = z4.w * sc.w + ps.w;
        float scl = hl < 2 ? (hl == 0 ? sc.x : sc.y) : (hl == 2 ? sc.z : sc.w);
        acc0 *= scl;
        acc1 *= scl;
        acc2 *= scl;
        acc3 *= scl;
        sp[u][l] = p;
        ssrc[u][l] = s;
        int lim = min(64, cnt - (tile << 6));
        const float* spf = (const float*)&sp[u][0];
        int jj = 0;
        for (; jj + 2 <= lim; jj += 2) {
            int s0 = __builtin_amdgcn_readfirstlane(ssrc[u][jj]);
            int s1 = __builtin_amdgcn_readfirstlane(ssrc[u][jj + 1]);
            float p0 = spf[jj * 4 + hl];
            float p1 = spf[jj * 4 + 4 + hl];
            uint2 r0 = *(const uint2*)(xp + (size_t)s0 * HID + 4 * l);
            uint2 r1 = *(const uint2*)(xp + (size_t)s1 * HID + 4 * l);
            acc0 += p0 * b2f_lo(r0.x) + p1 * b2f_lo(r1.x);
            acc1 += p0 * b2f_hi(r0.x) + p1 * b2f_hi(r1.x);
            acc2 += p0 * b2f_lo(r0.y) + p1 * b2f_lo(r1.y);
            acc3 += p0 * b2f_hi(r0.y) + p1 * b2f_hi(r1.y);
        }
        if (jj < lim) {
            int s0 = __builtin_amdgcn_readfirstlane(ssrc[u][jj]);
            float p0 = spf[jj * 4 + hl];
            uint2 r0 = *(const uint2*)(xp + (size_t)s0 * HID + 4 * l);
            acc0 += p0 * b2f_lo(r0.x);
            acc1 += p0 * b2f_hi(r0.x);
            acc2 += p0 * b2f_lo(r0.y);
            acc3 += p0 * b2f_hi(r0.y);
        }
    }
    // ---- fold in self-loop: ea_self = mean incoming eattr ----
    {
        float loop_ea = se / fmaxf((float)cnt, 1.0f);
        float4 asn = a_s4[n];
        float4 lgs;
        lgs.x = lrelu(asn.x + adn.x + loop_ea * wh.x);
        lgs.y = lrelu(asn.y + adn.y + loop_ea * wh.y);
        lgs.z = lrelu(asn.z + adn.z + loop_ea * wh.z);
        lgs.w = lrelu(asn.w + adn.w + loop_ea * wh.w);
        float4 mn;
        mn.x = fmaxf(m4.x, lgs.x);
        mn.y = fmaxf(m4.y, lgs.y);
        mn.z = fmaxf(m4.z, lgs.z);
        mn.w = fmaxf(m4.w, lgs.w);
        float4 so;
        so.x = __expf(m4.x - mn.x);
        so.y = __expf(m4.y - mn.y);
        so.z = __expf(m4.z - mn.z);
        so.w = __expf(m4.w - mn.w);
        float4 pf;
        pf.x = __expf(lgs.x - mn.x);
        pf.y = __expf(lgs.y - mn.y);
        pf.z = __expf(lgs.z - mn.z);
        pf.w = __expf(lgs.w - mn.w);
        z4.x = z4.x * so.x + pf.x;
        z4.y = z4.y * so.y + pf.y;
        z4.z = z4.z * so.z + pf.z;
        z4.w = z4.w * so.w + pf.w;
        float sol = hl < 2 ? (hl == 0 ? so.x : so.y) : (hl == 2 ? so.z : so.w);
        float psl = hl < 2 ? (hl == 0 ? pf.x : pf.y) : (hl == 2 ? pf.z : pf.w);
        uint2 rv = *(const uint2*)(xp + (size_t)n * HID + 4 * l);
        acc0 = acc0 * sol + psl * b2f_lo(rv.x);
        acc1 = acc1 * sol + psl * b2f_hi(rv.x);
        acc2 = acc2 * sol + psl * b2f_lo(rv.y);
        acc3 = acc3 * sol + psl * b2f_hi(rv.y);
    }
    float zh = hl < 2 ? (hl == 0 ? z4.x : z4.y) : (hl == 2 ? z4.z : z4.w);
    float zi = 1.0f / (zh + 1e-16f);
    float4 bi = bias4[l];
    float v0 = acc0 * zi + bi.x;
    float v1 = acc1 * zi + bi.y;
    float v2 = acc2 * zi + bi.z;
    float v3 = acc3 * zi + bi.w;
    float s1 = v0 + v1 + v2 + v3;
    float s2 = v0 * v0 + v1 * v1 + v2 * v2 + v3 * v3;
    #pragma unroll
    for (int off = 32; off; off >>= 1) {
        s1 += __shfl_xor(s1, off);
        s2 += __shfl_xor(s2, off);
    }
    float mu = s1 * (1.0f / HID);
    float var = s2 * (1.0f / HID) - mu * mu;
    float rstd = rsqrtf(var + 1e-5f);
    float4 g = gamma4[l], be = beta4[l], xr = x4[(size_t)n * 64 + l];
    float4 o;
    o.x = (v0 - mu) * rstd * g.x + be.x + xr.x;
    o.y = (v1 - mu) * rstd * g.y + be.y + xr.y;
    o.z = (v2 - mu) * rstd * g.z + be.z + xr.z;
    o.w = (v3 - mu) * rstd * g.w + be.w + xr.w;
    o.x = o.x > 0.f ? o.x : 0.f;
    o.y = o.y > 0.f ? o.y : 0.f;
    o.z = o.z > 0.f ? o.z : 0.f;
    o.w = o.w > 0.f ? o.w : 0.f;
    out4[(size_t)n * 64 + l] = o;
}

extern "C" void kernel_launch(void* const* d_in, const int* in_sizes, int n_in,
                              void* d_out, int out_size, void* d_ws,
                              size_t ws_size, hipStream_t stream) {
    const float* x        = (const float*)d_in[0];
    const int*   ei       = (const int*)d_in[1];
    const float* eattr    = (const float*)d_in[2];
    const float* W        = (const float*)d_in[3];
    const float* att_src  = (const float*)d_in[4];
    const float* att_dst  = (const float*)d_in[5];
    const float* We       = (const float*)d_in[6];
    const float* att_edge = (const float*)d_in[7];
    const float* bias     = (const float*)d_in[8];
    const float* gamma    = (const float*)d_in[9];
    const float* beta     = (const float*)d_in[10];

    int N = in_sizes[0] / HID;
    int E = in_sizes[1] / 2;
    const int* src = ei;
    const int* dst = ei + E;

    int MF = (N + 15) / 16;
    size_t NP = (size_t)MF * 16;

    // workspace layout (32-bit words)
    float* base = (float*)d_ws;
    unsigned short* Ap = (unsigned short*)base;                    // NP*128 w
    unsigned short* Bp = (unsigned short*)(base + NP * 128);       // 32768 w
    unsigned short* xp = (unsigned short*)(base + NP * 128 + 32768);  // NP*128
    float* a_s    = base + NP * 256 + 32768;                       // N*4
    float* a_d    = a_s + (size_t)N * 4;                           // N*4
    float* wedot  = a_d + (size_t)N * 4;                           // 4
    int* deg8     = (int*)(wedot + 4);                             // N*8
    int* pos      = deg8 + (size_t)N * 8;                          // E
    int* rowptr8  = pos + E;                                       // N*8+8
    int2* adj     = (int2*)(rowptr8 + (size_t)N * 8 + 8);          // E

    int M8 = N * 8;
    int ZB = (M8 / 4 + 255) / 256;
    k_zero<<<ZB, 256, 0, stream>>>((int4*)deg8, M8 / 4);

    int DBc = (E + 511) / 512;
    int XB = MF;
    k_prep<<<DBc + XB + 17, 256, 0, stream>>>(x, W, We, att_edge, dst, Ap, Bp,
                                              wedot, deg8, pos, N, E, DBc, XB);
    k_scan8<<<1, 1024, 0, stream>>>(deg8, rowptr8, M8);
    int MB = (MF + 3) / 4;
    int FB = (E + 511) / 512;
    k_fillmm<<<MB + FB, 256, 0, stream>>>(Ap, Bp, att_src, att_dst, xp, a_s,
                                          a_d, src, dst, eattr, rowptr8, pos,
                                          adj, N, MF, MB, E);
    k_gather_ln<<<(N + 3) / 4, 256, 0, stream>>>(
        adj, rowptr8, (const float4*)a_s, (const float4*)a_d, wedot, xp,
        (const float4*)x, (const float4*)bias, (const float4*)gamma,
        (const float4*)beta, (float4*)d_out, N);
}

// Round 8
// 88.625 us; speedup vs baseline: 2.5321x; 2.5321x over previous
//
#include <hip/hip_runtime.h>

#define HID 256
#define NH 4
#define NEG 0.2f

typedef __attribute__((ext_vector_type(8))) short short8;
typedef __attribute__((ext_vector_type(4))) float f32x4;

__device__ __forceinline__ unsigned short f2b(float f) {
    unsigned u = __float_as_uint(f);
    u = u + 0x7FFFu + ((u >> 16) & 1u);
    return (unsigned short)(u >> 16);
}
__device__ __forceinline__ float b2f_lo(unsigned u) {
    return __uint_as_float(u << 16);
}
__device__ __forceinline__ float b2f_hi(unsigned u) {
    return __uint_as_float(u & 0xFFFF0000u);
}
__device__ __forceinline__ float lrelu(float f) {
    return f > 0.f ? f : NEG * f;
}

// ---- K_zero: zero deg8 (N*8 ints) ----
__global__ __launch_bounds__(256) void k_zero(int4* __restrict__ deg8v,
                                              int n4) {
    int i = blockIdx.x * 256 + threadIdx.x;
    if (i < n4) deg8v[i] = make_int4(0, 0, 0, 0);
}

// ---- K_prep: [edge slot-capture (8-way split) | x->Ap pack | W->Bp pack |
//               wedot] ----
// frag layout: Ap[((fi*8+ks)*64+lane)*8+j] = A[fi*16+(lane&15)][ks*32+(lane>>4)*8+j]
__global__ __launch_bounds__(256) void k_prep(
    const float* __restrict__ x, const float* __restrict__ W,
    const float* __restrict__ We, const float* __restrict__ att_edge,
    const int* __restrict__ dst,
    unsigned short* __restrict__ Ap, unsigned short* __restrict__ Bp,
    float* __restrict__ wedot, int* __restrict__ deg8, int* __restrict__ pos,
    int N, int E, int DBc, int XB) {
    __shared__ unsigned short sm[4096];
    int b = blockIdx.x, t = threadIdx.x;
    if (b < DBc) {  // ---- slot capture: 2 edges/thread, 8-way split ----
        int e0 = b * 512 + t;
        int e1 = e0 + 256;
        if (e1 < E) {
            int d0 = dst[e0], d1 = dst[e1];
            int p0 = atomicAdd(&deg8[(d0 << 3) | (e0 & 7)], 1);
            int p1 = atomicAdd(&deg8[(d1 << 3) | (e1 & 7)], 1);
            pos[e0] = p0;
            pos[e1] = p1;
        } else if (e0 < E) {
            int d0 = dst[e0];
            pos[e0] = atomicAdd(&deg8[(d0 << 3) | (e0 & 7)], 1);
        }
        return;
    }
    int b2 = b - DBc;
    if (b2 < XB) {  // ---- pack x: one 16-row tile -> 8KB contiguous ----
        int fi = b2;
        int r = t >> 4;
        int row = fi * 16 + r;
        const float4* x4 = (const float4*)x;
        #pragma unroll
        for (int q = 0; q < 4; q++) {
            int c4 = (t & 15) + (q << 4);
            unsigned u0 = 0, u1 = 0;
            if (row < N) {
                float4 v = x4[(size_t)row * 64 + c4];
                u0 = (unsigned)f2b(v.x) | ((unsigned)f2b(v.y) << 16);
                u1 = (unsigned)f2b(v.z) | ((unsigned)f2b(v.w) << 16);
            }
            int k0 = c4 << 2;
            int ks = k0 >> 5, ko = k0 & 31;
            int lane = r + ((ko >> 3) << 4);
            int off = ks * 512 + lane * 8 + (ko & 7);
            *((uint2*)&sm[off]) = make_uint2(u0, u1);
        }
        __syncthreads();
        uint4* out = (uint4*)(Ap + (size_t)fi * 4096);
        const uint4* smv = (const uint4*)sm;
        out[t] = smv[t];
        out[256 + t] = smv[256 + t];
    } else if (b2 < XB + 16) {  // ---- pack W: one 16-col strip ----
        int n16 = b2 - XB;
        int k = t;
        int ks = k >> 5;
        int lhi = ((k & 31) >> 3) << 4;
        int j = k & 7;
        const float4* W4 = (const float4*)W;
        #pragma unroll
        for (int q = 0; q < 4; q++) {
            float4 v = W4[(size_t)k * 64 + n16 * 4 + q];
            int c = q << 2;
            sm[ks * 512 + (lhi + c + 0) * 8 + j] = f2b(v.x);
            sm[ks * 512 + (lhi + c + 1) * 8 + j] = f2b(v.y);
            sm[ks * 512 + (lhi + c + 2) * 8 + j] = f2b(v.z);
            sm[ks * 512 + (lhi + c + 3) * 8 + j] = f2b(v.w);
        }
        __syncthreads();
        uint4* out = (uint4*)(Bp + (size_t)n16 * 4096);
        const uint4* smv = (const uint4*)sm;
        out[t] = smv[t];
        out[256 + t] = smv[256 + t];
    } else {  // ---- wedot ----
        float v = We[t] * att_edge[t];
        #pragma unroll
        for (int off = 32; off; off >>= 1) v += __shfl_down(v, off);
        if ((t & 63) == 0) wedot[t >> 6] = v;
    }
}

// ---- K_scan8: tiled prefix scan over nodes; writes rowptr8[N*8+1] ----
// thread t <-> node tile*1024+t; coalesced int4-pair loads; LDS carry.
__global__ __launch_bounds__(1024) void k_scan8(const int4* __restrict__ deg8v,
                                                int* __restrict__ rowptr8,
                                                int N) {
    __shared__ int wsum[16], woff[16];
    __shared__ int carry_s, tot_s;
    int t = threadIdx.x, lane = t & 63, w = t >> 6;
    if (t == 0) carry_s = 0;
    __syncthreads();
    int ntile = (N + 1023) >> 10;
    for (int tile = 0; tile < ntile; tile++) {
        int node = (tile << 10) + t;
        int d8[8];
        int s = 0;
        if (node < N) {
            int4 lo = deg8v[node * 2];
            int4 hi = deg8v[node * 2 + 1];
            d8[0] = lo.x; d8[1] = lo.y; d8[2] = lo.z; d8[3] = lo.w;
            d8[4] = hi.x; d8[5] = hi.y; d8[6] = hi.z; d8[7] = hi.w;
            #pragma unroll
            for (int i = 0; i < 8; i++) s += d8[i];
        } else {
            #pragma unroll
            for (int i = 0; i < 8; i++) d8[i] = 0;
        }
        int incl = s;
        #pragma unroll
        for (int off = 1; off < 64; off <<= 1) {
            int up = __shfl_up(incl, off);
            if (lane >= off) incl += up;
        }
        if (lane == 63) wsum[w] = incl;
        __syncthreads();
        if (t < 16) {
            int v = wsum[t];
            int inc = v;
            #pragma unroll
            for (int off = 1; off < 16; off <<= 1) {
                int up = __shfl_up(inc, off);
                if (t >= off) inc += up;
            }
            woff[t] = inc - v;
            if (t == 15) tot_s = inc;
        }
        __syncthreads();
        if (node < N) {
            int run = carry_s + woff[w] + (incl - s);
            int4 o0, o1;
            o0.x = run;
            o0.y = run + d8[0];
            o0.z = o0.y + d8[1];
            o0.w = o0.z + d8[2];
            o1.x = o0.w + d8[3];
            o1.y = o1.x + d8[4];
            o1.z = o1.y + d8[5];
            o1.w = o1.z + d8[6];
            ((int4*)rowptr8)[node * 2] = o0;
            ((int4*)rowptr8)[node * 2 + 1] = o1;
        }
        __syncthreads();
        if (t == 0) carry_s += tot_s;
        __syncthreads();
    }
    if (t == 0) rowptr8[N * 8] = carry_s;
}

// ---- K_fillmm: fused [mfma xp=x@W + a_s/a_d epilogue | CSR scatter] ----
__global__ __launch_bounds__(256) void k_fillmm(
    const unsigned short* __restrict__ Ap, const unsigned short* __restrict__ Bp,
    const float* __restrict__ att_src, const float* __restrict__ att_dst,
    unsigned short* __restrict__ xp, float* __restrict__ a_s,
    float* __restrict__ a_d, const int* __restrict__ src,
    const int* __restrict__ dst, const float* __restrict__ eattr,
    const int* __restrict__ rowptr8, const int* __restrict__ pos,
    int2* __restrict__ adj, int N, int MF, int MB, int E) {
    int t = threadIdx.x;
    if ((int)blockIdx.x >= MB) {  // ---- CSR scatter (atomic-free) ----
        int fb = blockIdx.x - MB;
        int e0 = fb * 512 + t;
        int e1 = e0 + 256;
        if (e0 < E) {
            int d = dst[e0];
            int slot = rowptr8[(d << 3) | (e0 & 7)] + pos[e0];
            adj[slot] = make_int2(src[e0], __float_as_int(eattr[e0]));
        }
        if (e1 < E) {
            int d = dst[e1];
            int slot = rowptr8[(d << 3) | (e1 & 7)] + pos[e1];
            adj[slot] = make_int2(src[e1], __float_as_int(eattr[e1]));
        }
        return;
    }
    int w = t >> 6, l = t & 63;
    int fi0 = blockIdx.x * 4;
    const short8* A8 = (const short8*)Ap;
    const short8* B8 = (const short8*)Bp;
    f32x4 acc[4][4];
    #pragma unroll
    for (int mi = 0; mi < 4; mi++)
        #pragma unroll
        for (int ni = 0; ni < 4; ni++)
            acc[mi][ni] = (f32x4){0.f, 0.f, 0.f, 0.f};
    short8 zz = {0, 0, 0, 0, 0, 0, 0, 0};
    #pragma unroll
    for (int ks = 0; ks < 8; ks++) {
        short8 a[4], b[4];
        #pragma unroll
        for (int mi = 0; mi < 4; mi++) {
            int fi = fi0 + mi;
            a[mi] = (fi < MF) ? A8[(size_t)(fi * 8 + ks) * 64 + l] : zz;
        }
        #pragma unroll
        for (int ni = 0; ni < 4; ni++)
            b[ni] = B8[(size_t)(((w << 2) + ni) * 8 + ks) * 64 + l];
        #pragma unroll
        for (int mi = 0; mi < 4; mi++)
            #pragma unroll
            for (int ni = 0; ni < 4; ni++)
                acc[mi][ni] = __builtin_amdgcn_mfma_f32_16x16x32_bf16(
                    a[mi], b[ni], acc[mi][ni], 0, 0, 0);
    }
    int colb = w << 6;
    float asc[4], adc[4];
    #pragma unroll
    for (int ni = 0; ni < 4; ni++) {
        asc[ni] = att_src[colb + ni * 16 + (l & 15)];
        adc[ni] = att_dst[colb + ni * 16 + (l & 15)];
    }
    #pragma unroll
    for (int mi = 0; mi < 4; mi++) {
        int rowb = fi0 * 16 + mi * 16 + ((l >> 4) << 2);
        #pragma unroll
        for (int r = 0; r < 4; r++) {
            int row = rowb + r;
            float ps = 0.f, pd = 0.f;
            #pragma unroll
            for (int ni = 0; ni < 4; ni++) {
                float v = acc[mi][ni][r];
                ps += v * asc[ni];
                pd += v * adc[ni];
            }
            #pragma unroll
            for (int off = 1; off < 16; off <<= 1) {
                ps += __shfl_xor(ps, off);
                pd += __shfl_xor(pd, off);
            }
            if (row < N) {
                if ((l & 15) == 0) {
                    a_s[(row << 2) + w] = ps;
                    a_d[(row << 2) + w] = pd;
                }
                #pragma unroll
                for (int ni = 0; ni < 4; ni++)
                    xp[(size_t)row * HID + colb + ni * 16 + (l & 15)] =
                        f2b(acc[mi][ni][r]);
            }
        }
    }
}

// ---- K_gather_ln: wave-per-node online-softmax gather; self-loop folded
//      in at the end (loop_ea computed from the edges themselves) ----
__global__ __launch_bounds__(256) void k_gather_ln(
    const int2* __restrict__ adj, const int* __restrict__ rowptr8,
    const float4* __restrict__ a_s4, const float4* __restrict__ a_d4,
    const float* __restrict__ wedot, const unsigned short* __restrict__ xp,
    const float4* __restrict__ x4, const float4* __restrict__ bias4,
    const float4* __restrict__ gamma4, const float4* __restrict__ beta4,
    float4* __restrict__ out4, int N) {
    __shared__ float4 sp[4][64];
    __shared__ int ssrc[4][64];
    int t = threadIdx.x;
    int u = t >> 6, l = t & 63, hl = l >> 4;
    int n = blockIdx.x * 4 + u;
    if (n >= N) return;
    int beg = rowptr8[n << 3];
    int cnt = rowptr8[(n + 1) << 3] - beg;
    float4 adn = a_d4[n];
    float4 wh = *(const float4*)wedot;
    float4 m4 = {-1e30f, -1e30f, -1e30f, -1e30f};
    float4 z4 = {0.f, 0.f, 0.f, 0.f};
    float acc0 = 0.f, acc1 = 0.f, acc2 = 0.f, acc3 = 0.f;
    float se = 0.f;
    int ntile = (cnt + 63) >> 6;
    for (int tile = 0; tile < ntile; tile++) {
        int j = (tile << 6) + l;
        float4 lg = {-1e30f, -1e30f, -1e30f, -1e30f};
        float ea = 0.f;
        int s = 0;
        if (j < cnt) {
            int2 a = adj[beg + j];
            s = a.x;
            ea = __int_as_float(a.y);
            float4 as_ = a_s4[s];
            lg.x = lrelu(as_.x + adn.x + ea * wh.x);
            lg.y = lrelu(as_.y + adn.y + ea * wh.y);
            lg.z = lrelu(as_.z + adn.z + ea * wh.z);
            lg.w = lrelu(as_.w + adn.w + ea * wh.w);
        }
        float4 cm = lg;
        float es = ea;
        #pragma unroll
        for (int off = 32; off; off >>= 1) {
            cm.x = fmaxf(cm.x, __shfl_xor(cm.x, off));
            cm.y = fmaxf(cm.y, __shfl_xor(cm.y, off));
            cm.z = fmaxf(cm.z, __shfl_xor(cm.z, off));
            cm.w = fmaxf(cm.w, __shfl_xor(cm.w, off));
            es += __shfl_xor(es, off);
        }
        se += es;
        float4 mn;
        mn.x = fmaxf(m4.x, cm.x);
        mn.y = fmaxf(m4.y, cm.y);
        mn.z = fmaxf(m4.z, cm.z);
        mn.w = fmaxf(m4.w, cm.w);
        float4 sc;
        sc.x = __expf(m4.x - mn.x);
        sc.y = __expf(m4.y - mn.y);
        sc.z = __expf(m4.z - mn.z);
        sc.w = __expf(m4.w - mn.w);
        float4 p;
        p.x = __expf(lg.x - mn.x);
        p.y = __expf(lg.y - mn.y);
        p.z = __expf(lg.z - mn.z);
        p.w = __expf(lg.w - mn.w);
        m4 = mn;
        float4 ps = p;
        #pragma unroll
        for (int off = 32; off; off >>= 1) {
            ps.x += __shfl_xor(ps.x, off);
            ps.y += __shfl_xor(ps.y, off);
            ps.z += __shfl_xor(ps.z, off);
            ps.w += __shfl_xor(ps.w, off);
        }
        z4.x = z4.x * sc.x + ps.x;
        z4.y = z4.y * sc.y + ps.y;
        z4.z = z4.z * sc.z + ps.z;
        z4.w = z4.w * sc.w + ps.w;
        float scl = hl < 2 ? (hl == 0 ? sc.x : sc.y) : (hl == 2 ? sc.z : sc.w);
        acc0 *= scl;
        acc1 *= scl;
        acc2 *= scl;
        acc3 *= scl;
        sp[u][l] = p;
        ssrc[u][l] = s;
        int lim = min(64, cnt - (tile << 6));
        const float* spf = (const float*)&sp[u][0];
        int jj = 0;
        for (; jj + 2 <= lim; jj += 2) {
            int s0 = __builtin_amdgcn_readfirstlane(ssrc[u][jj]);
            int s1 = __builtin_amdgcn_readfirstlane(ssrc[u][jj + 1]);
            float p0 = spf[jj * 4 + hl];
            float p1 = spf[jj * 4 + 4 + hl];
            uint2 r0 = *(const uint2*)(xp + (size_t)s0 * HID + 4 * l);
            uint2 r1 = *(const uint2*)(xp + (size_t)s1 * HID + 4 * l);
            acc0 += p0 * b2f_lo(r0.x) + p1 * b2f_lo(r1.x);
            acc1 += p0 * b2f_hi(r0.x) + p1 * b2f_hi(r1.x);
            acc2 += p0 * b2f_lo(r0.y) + p1 * b2f_lo(r1.y);
            acc3 += p0 * b2f_hi(r0.y) + p1 * b2f_hi(r1.y);
        }
        if (jj < lim) {
            int s0 = __builtin_amdgcn_readfirstlane(ssrc[u][jj]);
            float p0 = spf[jj * 4 + hl];
            uint2 r0 = *(const uint2*)(xp + (size_t)s0 * HID + 4 * l);
            acc0 += p0 * b2f_lo(r0.x);
            acc1 += p0 * b2f_hi(r0.x);
            acc2 += p0 * b2f_lo(r0.y);
            acc3 += p0 * b2f_hi(r0.y);
        }
    }
    // ---- fold in self-loop: ea_self = mean incoming eattr ----
    {
        float loop_ea = se / fmaxf((float)cnt, 1.0f);
        float4 asn = a_s4[n];
        float4 lgs;
        lgs.x = lrelu(asn.x + adn.x + loop_ea * wh.x);
        lgs.y = lrelu(asn.y + adn.y + loop_ea * wh.y);
        lgs.z = lrelu(asn.z + adn.z + loop_ea * wh.z);
        lgs.w = lrelu(asn.w + adn.w + loop_ea * wh.w);
        float4 mn;
        mn.x = fmaxf(m4.x, lgs.x);
        mn.y = fmaxf(m4.y, lgs.y);
        mn.z = fmaxf(m4.z, lgs.z);
        mn.w = fmaxf(m4.w, lgs.w);
        float4 so;
        so.x = __expf(m4.x - mn.x);
        so.y = __expf(m4.y - mn.y);
        so.z = __expf(m4.z - mn.z);
        so.w = __expf(m4.w - mn.w);
        float4 pf;
        pf.x = __expf(lgs.x - mn.x);
        pf.y = __expf(lgs.y - mn.y);
        pf.z = __expf(lgs.z - mn.z);
        pf.w = __expf(lgs.w - mn.w);
        z4.x = z4.x * so.x + pf.x;
        z4.y = z4.y * so.y + pf.y;
        z4.z = z4.z * so.z + pf.z;
        z4.w = z4.w * so.w + pf.w;
        float sol = hl < 2 ? (hl == 0 ? so.x : so.y) : (hl == 2 ? so.z : so.w);
        float psl = hl < 2 ? (hl == 0 ? pf.x : pf.y) : (hl == 2 ? pf.z : pf.w);
        uint2 rv = *(const uint2*)(xp + (size_t)n * HID + 4 * l);
        acc0 = acc0 * sol + psl * b2f_lo(rv.x);
        acc1 = acc1 * sol + psl * b2f_hi(rv.x);
        acc2 = acc2 * sol + psl * b2f_lo(rv.y);
        acc3 = acc3 * sol + psl * b2f_hi(rv.y);
    }
    float zh = hl < 2 ? (hl == 0 ? z4.x : z4.y) : (hl == 2 ? z4.z : z4.w);
    float zi = 1.0f / (zh + 1e-16f);
    float4 bi = bias4[l];
    float v0 = acc0 * zi + bi.x;
    float v1 = acc1 * zi + bi.y;
    float v2 = acc2 * zi + bi.z;
    float v3 = acc3 * zi + bi.w;
    float s1 = v0 + v1 + v2 + v3;
    float s2 = v0 * v0 + v1 * v1 + v2 * v2 + v3 * v3;
    #pragma unroll
    for (int off = 32; off; off >>= 1) {
        s1 += __shfl_xor(s1, off);
        s2 += __shfl_xor(s2, off);
    }
    float mu = s1 * (1.0f / HID);
    float var = s2 * (1.0f / HID) - mu * mu;
    float rstd = rsqrtf(var + 1e-5f);
    float4 g = gamma4[l], be = beta4[l], xr = x4[(size_t)n * 64 + l];
    float4 o;
    o.x = (v0 - mu) * rstd * g.x + be.x + xr.x;
    o.y = (v1 - mu) * rstd * g.y + be.y + xr.y;
    o.z = (v2 - mu) * rstd * g.z + be.z + xr.z;
    o.w = (v3 - mu) * rstd * g.w + be.w + xr.w;
    o.x = o.x > 0.f ? o.x : 0.f;
    o.y = o.y > 0.f ? o.y : 0.f;
    o.z = o.z > 0.f ? o.z : 0.f;
    o.w = o.w > 0.f ? o.w : 0.f;
    out4[(size_t)n * 64 + l] = o;
}

extern "C" void kernel_launch(void* const* d_in, const int* in_sizes, int n_in,
                              void* d_out, int out_size, void* d_ws,
                              size_t ws_size, hipStream_t stream) {
    const float* x        = (const float*)d_in[0];
    const int*   ei       = (const int*)d_in[1];
    const float* eattr    = (const float*)d_in[2];
    const float* W        = (const float*)d_in[3];
    const float* att_src  = (const float*)d_in[4];
    const float* att_dst  = (const float*)d_in[5];
    const float* We       = (const float*)d_in[6];
    const float* att_edge = (const float*)d_in[7];
    const float* bias     = (const float*)d_in[8];
    const float* gamma    = (const float*)d_in[9];
    const float* beta     = (const float*)d_in[10];

    int N = in_sizes[0] / HID;
    int E = in_sizes[1] / 2;
    const int* src = ei;
    const int* dst = ei + E;

    int MF = (N + 15) / 16;
    size_t NP = (size_t)MF * 16;

    // workspace layout (32-bit words)
    float* base = (float*)d_ws;
    unsigned short* Ap = (unsigned short*)base;                    // NP*128 w
    unsigned short* Bp = (unsigned short*)(base + NP * 128);       // 32768 w
    unsigned short* xp = (unsigned short*)(base + NP * 128 + 32768);  // NP*128
    float* a_s    = base + NP * 256 + 32768;                       // N*4
    float* a_d    = a_s + (size_t)N * 4;                           // N*4
    float* wedot  = a_d + (size_t)N * 4;                           // 4 (+pad)
    int* deg8     = (int*)(wedot + 8);                             // N*8
    int* pos      = deg8 + (size_t)N * 8;                          // E
    int* rowptr8  = pos + E;                                       // N*8+8
    int2* adj     = (int2*)(rowptr8 + (size_t)N * 8 + 8);          // E

    int M8 = N * 8;
    int ZB = (M8 / 4 + 255) / 256;
    k_zero<<<ZB, 256, 0, stream>>>((int4*)deg8, M8 / 4);

    int DBc = (E + 511) / 512;
    int XB = MF;
    k_prep<<<DBc + XB + 17, 256, 0, stream>>>(x, W, We, att_edge, dst, Ap, Bp,
                                              wedot, deg8, pos, N, E, DBc, XB);
    k_scan8<<<1, 1024, 0, stream>>>((const int4*)deg8, rowptr8, N);
    int MB = (MF + 3) / 4;
    int FB = (E + 511) / 512;
    k_fillmm<<<MB + FB, 256, 0, stream>>>(Ap, Bp, att_src, att_dst, xp, a_s,
                                          a_d, src, dst, eattr, rowptr8, pos,
                                          adj, N, MF, MB, E);
    k_gather_ln<<<(N + 3) / 4, 256, 0, stream>>>(
        adj, rowptr8, (const float4*)a_s, (const float4*)a_d, wedot, xp,
        (const float4*)x, (const float4*)bias, (const float4*)gamma,
        (const float4*)beta, (float4*)d_out, N);
}